// Round 7
// baseline (161.023 us; speedup 1.0000x reference)
//
#include <hip/hip_runtime.h>
#include <hip/hip_bf16.h>

// Problem constants (GCN_66649302499531)
#define NN 20000
#define NG 400
#define D_IN 128
#define H1 256
#define H2 256
#define D_OUT 128
#define NB_RANK ((NN + 255) / 256)   // 79
#define NB_PAD 80
#define WT_ELEMS (D_IN * H1 + H1 * H2 + H2 * D_OUT)   // 131072

typedef __attribute__((ext_vector_type(8))) short short8;
typedef __attribute__((ext_vector_type(4))) short short4v;
typedef __attribute__((ext_vector_type(4))) float floatx4;

__device__ __forceinline__ short f2b(float f) {
    __hip_bfloat16 h = __float2bfloat16(f);
    return *(short*)&h;
}

// ---------------------------------------------------------------------------
// Rank / permutation kernels (R4-proven structure, kept as separate launches).
// rank[j] = #{i<j : idx[i]==idx[j]};  deg[j]=rank[j]+1;  dis[j]=rsqrt(deg[j])
// perm: nodes sorted by (group, index) -> aggregation is a segmented prefix.
// ---------------------------------------------------------------------------

__global__ __launch_bounds__(256) void rank1_kernel(
    const int* __restrict__ idx, int* __restrict__ lrank,
    int* __restrict__ blockhist)
{
    __shared__ int sg[256];
    __shared__ int hist[NG];
    int t = threadIdx.x;
    int b = blockIdx.x;
    int j = b * 256 + t;
    for (int g = t; g < NG; g += 256) hist[g] = 0;
    int g = (j < NN) ? idx[j] : -1;
    sg[t] = g;
    __syncthreads();
    if (g >= 0) atomicAdd(&hist[g], 1);
    int r = 0;
    for (int s = 0; s < t; ++s) {
        if (sg[s] == g) r++;
    }
    __syncthreads();
    if (j < NN) lrank[j] = r;
    for (int gg = t; gg < NG; gg += 256) blockhist[gg * NB_PAD + b] = hist[gg];
}

__global__ __launch_bounds__(512) void rank2_kernel(
    const int* __restrict__ blockhist, int* __restrict__ blockoff,
    int* __restrict__ gs)
{
    __shared__ int tot[512];
    int g = threadIdx.x;
    int run = 0;
    if (g < NG) {
        int4 buf[NB_PAD / 4];
        const int4* src = (const int4*)(blockhist + g * NB_PAD);
#pragma unroll
        for (int i = 0; i < NB_PAD / 4; ++i) buf[i] = src[i];
        const int* bi = (const int*)buf;
#pragma unroll
        for (int b = 0; b < NB_RANK; ++b) {
            blockoff[g * NB_PAD + b] = run;
            run += bi[b];
        }
    }
    tot[threadIdx.x] = (g < NG) ? run : 0;
    __syncthreads();
#pragma unroll
    for (int off = 1; off < 512; off <<= 1) {
        int v = (threadIdx.x >= off) ? tot[threadIdx.x - off] : 0;
        __syncthreads();
        tot[threadIdx.x] += v;
        __syncthreads();
    }
    if (threadIdx.x == 0) gs[0] = 0;
    if (threadIdx.x < NG) gs[threadIdx.x + 1] = tot[threadIdx.x];
}

__global__ __launch_bounds__(256) void rank3_kernel(
    const int* __restrict__ idx, const int* __restrict__ lrank,
    const int* __restrict__ blockoff, const int* __restrict__ gs,
    float* __restrict__ dis, int* __restrict__ perm)
{
    int j = blockIdx.x * 256 + threadIdx.x;
    if (j >= NN) return;
    int g = idx[j];
    int r = blockoff[g * NB_PAD + blockIdx.x] + lrank[j];
    dis[j] = rsqrtf((float)(r + 1));
    perm[gs[g] + r] = j;
}

// ---------------------------------------------------------------------------
// All three weight transposes (fp32 [K][N] -> bf16 [N][K]) in one launch.
// ---------------------------------------------------------------------------

__global__ __launch_bounds__(256) void wt_all(
    const float* __restrict__ W1, const float* __restrict__ W2,
    const float* __restrict__ W3, __hip_bfloat16* __restrict__ Wt1,
    __hip_bfloat16* __restrict__ Wt2, __hip_bfloat16* __restrict__ Wt3)
{
    int o = blockIdx.x * 256 + threadIdx.x;
    if (o < D_IN * H1) {                       // W1: K=128, N=256
        int n = o / D_IN, k = o - n * D_IN;
        Wt1[o] = __float2bfloat16(W1[(size_t)k * H1 + n]);
    } else if (o < D_IN * H1 + H1 * H2) {      // W2: K=256, N=256
        int p = o - D_IN * H1;
        int n = p / H1, k = p - n * H1;
        Wt2[p] = __float2bfloat16(W2[(size_t)k * H2 + n]);
    } else if (o < WT_ELEMS) {                 // W3: K=256, N=128
        int p = o - D_IN * H1 - H1 * H2;
        int n = p / H2, k = p - n * H2;
        Wt3[p] = __float2bfloat16(W3[(size_t)k * D_OUT + n]);
    }
}

// ---------------------------------------------------------------------------
// Fused per-group pipeline, one block (256 thr, 4 waves) per group, chunks of
// 64 members. All scans are MFMA triangular matmuls (B = lower-tri ones,
// generated in registers); prefix carries live in registers (shfl update).
// EVERY scan input is pre-scaled by dis[i]: scan1 at staging (x*sd), scan2 in
// GEMM1's epilogue (h1*sd), scan3 in GEMM3's epilogue (P*sd).
//   T1 xt[c][r] -> scan1 -> A1[j][c] -> GEMM1(A=A1,B=Wt1)*sd -> T2 h1t[c][r]
//   -> scan2 -> A2[j][c] -> GEMM2(A=Wt2,B=A2) -> HB h2[j][c]
//   -> GEMM3(A=HB,B=Wt3)*sd -> T3 Pt[d][r]
//   -> scan3 (+b3,relu) -> F[j][d] fp32 -> LayerNorm -> out
// Rows >= mt carry sd=0 so padded rows contribute nothing.
// ---------------------------------------------------------------------------

#define ST1 72
#define SA1 136
#define ST2 72
#define SA2 264
#define SH2 264
#define ST3 72
#define SF 132

__global__ __launch_bounds__(256) void fused_gcn(
    const float* __restrict__ x,
    const __hip_bfloat16* __restrict__ Wt1_,
    const __hip_bfloat16* __restrict__ Wt2_,
    const __hip_bfloat16* __restrict__ Wt3_,
    const float* __restrict__ b1, const float* __restrict__ b2,
    const float* __restrict__ b3,
    const float* __restrict__ gamma, const float* __restrict__ beta,
    const float* __restrict__ dis, const int* __restrict__ perm,
    const int* __restrict__ gs,
    float* __restrict__ out)
{
    __shared__ __align__(16) char RA[36864];   // T1 | T2 | HB | F
    __shared__ __align__(16) char RB[33792];   // A1 | A2 | T3
    __shared__ __align__(16) float b2s[256];
    __shared__ __align__(16) float b3s[128];
    __shared__ __align__(16) float sd[64];
    __shared__ int sp[64];

    short* T1 = (short*)RA;
    short* T2 = (short*)RA;
    short* HB = (short*)RA;
    float* F  = (float*)RA;
    short* A1 = (short*)RB;
    short* A2 = (short*)RB;
    short* T3 = (short*)RB;

    const short* Wt1 = (const short*)Wt1_;
    const short* Wt2 = (const short*)Wt2_;
    const short* Wt3 = (const short*)Wt3_;

    int tid = threadIdx.x;
    int w = tid >> 6;
    int lane = tid & 63;
    int quad = lane >> 4;
    int l15 = lane & 15;

    int g = blockIdx.x;
    int s = gs[g], cnt = gs[g + 1] - s;
    if (cnt <= 0) return;

    b2s[tid] = b2[tid];
    if (tid < 128) b3s[tid] = b3[tid];

    float bj1[4];
#pragma unroll
    for (int nt = 0; nt < 4; ++nt) bj1[nt] = b1[(w * 4 + nt) * 16 + l15];
    float2 gmv = *(const float2*)&gamma[lane * 2];
    float2 btv = *(const float2*)&beta[lane * 2];

    // Lower-triangular-ones B-fragments: Lt[nt][k2] element e has
    // (i = k2*32+quad*8+e) <= (j = nt*16+l15)  ->  bf16 1.0 else 0.
    short8 Lt[4][2];
#pragma unroll
    for (int nt = 0; nt < 4; ++nt)
#pragma unroll
        for (int k2 = 0; k2 < 2; ++k2) {
            int thr = nt * 16 + l15 - k2 * 32 - quad * 8;
#pragma unroll
            for (int e = 0; e < 8; ++e)
                Lt[nt][k2][e] = (e <= thr) ? (short)0x3F80 : (short)0;
        }

    float c1[2][4], c2[4][4], c3[2][4];
#pragma unroll
    for (int i = 0; i < 4; ++i)
#pragma unroll
        for (int r = 0; r < 4; ++r) {
            if (i < 2) { c1[i][r] = 0.f; c3[i][r] = 0.f; }
            c2[i][r] = 0.f;
        }

    for (int base = 0; base < cnt; base += 64) {
        int mt = min(64, cnt - base);
        __syncthreads();   // prev chunk LN done with F/sp
        if (tid < 64) {
            int p = (tid < mt) ? perm[s + base + tid] : perm[s];
            sp[tid] = p;
            sd[tid] = (tid < mt) ? dis[p] : 0.0f;
        }
        __syncthreads();

        float djn[4];
#pragma unroll
        for (int nt = 0; nt < 4; ++nt) djn[nt] = sd[nt * 16 + l15];

        // ---- stage x -> T1: xt[c][r] = bf16(x[sp[r]][c] * sd[r]) ----
        {
            int c = tid & 127;
            int rb0 = (tid >> 7) * 8;
#pragma unroll
            for (int p = 0; p < 4; ++p) {
                int rb = rb0 + p * 16;
                float v[8];
#pragma unroll
                for (int e = 0; e < 8; ++e)
                    v[e] = x[(size_t)sp[rb + e] * D_IN + c] * sd[rb + e];
                short8 o;
#pragma unroll
                for (int e = 0; e < 8; ++e) o[e] = f2b(v[e]);
                *(short8*)&T1[c * ST1 + rb] = o;
            }
        }
        __syncthreads();

        // ---- scan1 (MFMA): A1[j][c] = dj*(c1 + cumsum) ----
        {
            floatx4 acc[2][4];
#pragma unroll
            for (int i = 0; i < 2; ++i)
#pragma unroll
                for (int nt = 0; nt < 4; ++nt) acc[i][nt] = (floatx4)0.0f;
#pragma unroll
            for (int k2 = 0; k2 < 2; ++k2) {
                short8 af[2];
#pragma unroll
                for (int i = 0; i < 2; ++i)
                    af[i] = *(const short8*)&T1[((2 * w + i) * 16 + l15) * ST1 + k2 * 32 + quad * 8];
#pragma unroll
                for (int i = 0; i < 2; ++i)
#pragma unroll
                    for (int nt = 0; nt < 4; ++nt)
                        acc[i][nt] = __builtin_amdgcn_mfma_f32_16x16x32_bf16(
                            af[i], Lt[nt][k2], acc[i][nt], 0, 0, 0);
            }
#pragma unroll
            for (int i = 0; i < 2; ++i) {
                float nc[4] = {0.f, 0.f, 0.f, 0.f};
#pragma unroll
                for (int nt = 0; nt < 4; ++nt) {
                    float tmp[4];
#pragma unroll
                    for (int r = 0; r < 4; ++r) tmp[r] = acc[i][nt][r] + c1[i][r];
                    if (nt == 3) {
#pragma unroll
                        for (int r = 0; r < 4; ++r) nc[r] = tmp[r];
                    }
                    short4v o4;
#pragma unroll
                    for (int r = 0; r < 4; ++r) o4[r] = f2b(tmp[r] * djn[nt]);
                    *(short4v*)&A1[(nt * 16 + l15) * SA1 + (2 * w + i) * 16 + quad * 4] = o4;
                }
#pragma unroll
                for (int r = 0; r < 4; ++r)
                    c1[i][r] = __shfl(nc[r], (lane & 48) + 15);
            }
        }
        __syncthreads();

        // ---- GEMM1: h1t[c][j] = relu(A1 @ Wt1^T + b1) * sd[j]
        //      (A=A1 m=j, B=Wt1 n=c; epilogue pre-scales scan2's input) ----
        {
            floatx4 acc[4][4];
#pragma unroll
            for (int i = 0; i < 4; ++i)
#pragma unroll
                for (int j = 0; j < 4; ++j) acc[i][j] = (floatx4)0.0f;
#pragma unroll
            for (int kk = 0; kk < 4; ++kk) {   // K = 128
                short8 af[4], bf[4];
#pragma unroll
                for (int i = 0; i < 4; ++i)
                    af[i] = *(const short8*)&A1[(i * 16 + l15) * SA1 + kk * 32 + quad * 8];
#pragma unroll
                for (int nt = 0; nt < 4; ++nt)
                    bf[nt] = *(const short8*)&Wt1[((size_t)(w * 4 + nt) * 16 + l15) * D_IN + kk * 32 + quad * 8];
#pragma unroll
                for (int i = 0; i < 4; ++i)
#pragma unroll
                    for (int nt = 0; nt < 4; ++nt)
                        acc[i][nt] = __builtin_amdgcn_mfma_f32_16x16x32_bf16(
                            af[i], bf[nt], acc[i][nt], 0, 0, 0);
            }
#pragma unroll
            for (int i = 0; i < 4; ++i) {
                float4 sdv = *(const float4*)&sd[i * 16 + quad * 4];   // sd[j]
#pragma unroll
                for (int nt = 0; nt < 4; ++nt) {
                    short4v o4;
                    o4[0] = f2b(fmaxf(acc[i][nt][0] + bj1[nt], 0.0f) * sdv.x);
                    o4[1] = f2b(fmaxf(acc[i][nt][1] + bj1[nt], 0.0f) * sdv.y);
                    o4[2] = f2b(fmaxf(acc[i][nt][2] + bj1[nt], 0.0f) * sdv.z);
                    o4[3] = f2b(fmaxf(acc[i][nt][3] + bj1[nt], 0.0f) * sdv.w);
                    *(short4v*)&T2[((w * 4 + nt) * 16 + l15) * ST2 + i * 16 + quad * 4] = o4;
                }
            }
        }
        __syncthreads();

        // ---- scan2 (MFMA): A2[j][c] = dj*(c2 + cumsum(h1t)) ----
        {
            floatx4 acc[4][4];
#pragma unroll
            for (int i = 0; i < 4; ++i)
#pragma unroll
                for (int nt = 0; nt < 4; ++nt) acc[i][nt] = (floatx4)0.0f;
#pragma unroll
            for (int k2 = 0; k2 < 2; ++k2) {
                short8 af[4];
#pragma unroll
                for (int i = 0; i < 4; ++i)
                    af[i] = *(const short8*)&T2[((4 * w + i) * 16 + l15) * ST2 + k2 * 32 + quad * 8];
#pragma unroll
                for (int i = 0; i < 4; ++i)
#pragma unroll
                    for (int nt = 0; nt < 4; ++nt)
                        acc[i][nt] = __builtin_amdgcn_mfma_f32_16x16x32_bf16(
                            af[i], Lt[nt][k2], acc[i][nt], 0, 0, 0);
            }
#pragma unroll
            for (int i = 0; i < 4; ++i) {
                float nc[4] = {0.f, 0.f, 0.f, 0.f};
#pragma unroll
                for (int nt = 0; nt < 4; ++nt) {
                    float tmp[4];
#pragma unroll
                    for (int r = 0; r < 4; ++r) tmp[r] = acc[i][nt][r] + c2[i][r];
                    if (nt == 3) {
#pragma unroll
                        for (int r = 0; r < 4; ++r) nc[r] = tmp[r];
                    }
                    short4v o4;
#pragma unroll
                    for (int r = 0; r < 4; ++r) o4[r] = f2b(tmp[r] * djn[nt]);
                    *(short4v*)&A2[(nt * 16 + l15) * SA2 + (4 * w + i) * 16 + quad * 4] = o4;
                }
#pragma unroll
                for (int r = 0; r < 4; ++r)
                    c2[i][r] = __shfl(nc[r], (lane & 48) + 15);
            }
        }
        __syncthreads();

        // ---- GEMM2: h2[j][c2] = relu(A2 @ Wt2^T + b2)  (A=Wt2 m=c2, B=A2 n=j) ----
        {
            floatx4 acc[4][4];
#pragma unroll
            for (int i = 0; i < 4; ++i)
#pragma unroll
                for (int nt = 0; nt < 4; ++nt) acc[i][nt] = (floatx4)0.0f;
#pragma unroll
            for (int kk = 0; kk < 8; ++kk) {   // K = 256
                short8 af[4], bf[4];
#pragma unroll
                for (int i = 0; i < 4; ++i)
                    af[i] = *(const short8*)&Wt2[((size_t)(w * 4 + i) * 16 + l15) * H1 + kk * 32 + quad * 8];
#pragma unroll
                for (int nt = 0; nt < 4; ++nt)
                    bf[nt] = *(const short8*)&A2[(nt * 16 + l15) * SA2 + kk * 32 + quad * 8];
#pragma unroll
                for (int i = 0; i < 4; ++i)
#pragma unroll
                    for (int nt = 0; nt < 4; ++nt)
                        acc[i][nt] = __builtin_amdgcn_mfma_f32_16x16x32_bf16(
                            af[i], bf[nt], acc[i][nt], 0, 0, 0);
            }
#pragma unroll
            for (int i = 0; i < 4; ++i) {
                float4 bb = *(const float4*)&b2s[(w * 4 + i) * 16 + quad * 4];
#pragma unroll
                for (int nt = 0; nt < 4; ++nt) {
                    short4v o4;
                    o4[0] = f2b(fmaxf(acc[i][nt][0] + bb.x, 0.0f));
                    o4[1] = f2b(fmaxf(acc[i][nt][1] + bb.y, 0.0f));
                    o4[2] = f2b(fmaxf(acc[i][nt][2] + bb.z, 0.0f));
                    o4[3] = f2b(fmaxf(acc[i][nt][3] + bb.w, 0.0f));
                    *(short4v*)&HB[(nt * 16 + l15) * SH2 + (w * 4 + i) * 16 + quad * 4] = o4;
                }
            }
        }
        __syncthreads();

        // ---- GEMM3: Pt[d][j] = (h2 @ Wt3^T)[j][d] * sd[j]  (A=HB m=j, B=Wt3 n=d) ----
        {
            floatx4 acc[4][2];
#pragma unroll
            for (int i = 0; i < 4; ++i)
#pragma unroll
                for (int jn = 0; jn < 2; ++jn) acc[i][jn] = (floatx4)0.0f;
#pragma unroll
            for (int kk = 0; kk < 8; ++kk) {   // K = 256
                short8 af[4], bf[2];
#pragma unroll
                for (int i = 0; i < 4; ++i)
                    af[i] = *(const short8*)&HB[(i * 16 + l15) * SH2 + kk * 32 + quad * 8];
#pragma unroll
                for (int jn = 0; jn < 2; ++jn)
                    bf[jn] = *(const short8*)&Wt3[((size_t)(2 * w + jn) * 16 + l15) * H2 + kk * 32 + quad * 8];
#pragma unroll
                for (int i = 0; i < 4; ++i)
#pragma unroll
                    for (int jn = 0; jn < 2; ++jn)
                        acc[i][jn] = __builtin_amdgcn_mfma_f32_16x16x32_bf16(
                            af[i], bf[jn], acc[i][jn], 0, 0, 0);
            }
#pragma unroll
            for (int i = 0; i < 4; ++i) {
                float4 sdv = *(const float4*)&sd[i * 16 + quad * 4];
#pragma unroll
                for (int jn = 0; jn < 2; ++jn) {
                    short4v o4;
                    o4[0] = f2b(acc[i][jn][0] * sdv.x);
                    o4[1] = f2b(acc[i][jn][1] * sdv.y);
                    o4[2] = f2b(acc[i][jn][2] * sdv.z);
                    o4[3] = f2b(acc[i][jn][3] * sdv.w);
                    *(short4v*)&T3[((2 * w + jn) * 16 + l15) * ST3 + i * 16 + quad * 4] = o4;
                }
            }
        }
        __syncthreads();

        // ---- scan3 (MFMA): F[j][d] = relu(dj*(c3 + cumsum(Pt)) + b3) fp32 ----
        {
            floatx4 acc[2][4];
#pragma unroll
            for (int i = 0; i < 2; ++i)
#pragma unroll
                for (int nt = 0; nt < 4; ++nt) acc[i][nt] = (floatx4)0.0f;
#pragma unroll
            for (int k2 = 0; k2 < 2; ++k2) {
                short8 af[2];
#pragma unroll
                for (int i = 0; i < 2; ++i)
                    af[i] = *(const short8*)&T3[((2 * w + i) * 16 + l15) * ST3 + k2 * 32 + quad * 8];
#pragma unroll
                for (int i = 0; i < 2; ++i)
#pragma unroll
                    for (int nt = 0; nt < 4; ++nt)
                        acc[i][nt] = __builtin_amdgcn_mfma_f32_16x16x32_bf16(
                            af[i], Lt[nt][k2], acc[i][nt], 0, 0, 0);
            }
#pragma unroll
            for (int i = 0; i < 2; ++i) {
                float4 bb = *(const float4*)&b3s[(2 * w + i) * 16 + quad * 4];
                float nc[4] = {0.f, 0.f, 0.f, 0.f};
#pragma unroll
                for (int nt = 0; nt < 4; ++nt) {
                    float tmp[4];
#pragma unroll
                    for (int r = 0; r < 4; ++r) tmp[r] = acc[i][nt][r] + c3[i][r];
                    if (nt == 3) {
#pragma unroll
                        for (int r = 0; r < 4; ++r) nc[r] = tmp[r];
                    }
                    float4 o;
                    o.x = fmaxf(tmp[0] * djn[nt] + bb.x, 0.0f);
                    o.y = fmaxf(tmp[1] * djn[nt] + bb.y, 0.0f);
                    o.z = fmaxf(tmp[2] * djn[nt] + bb.z, 0.0f);
                    o.w = fmaxf(tmp[3] * djn[nt] + bb.w, 0.0f);
                    *(float4*)&F[(nt * 16 + l15) * SF + (2 * w + i) * 16 + quad * 4] = o;
                }
#pragma unroll
                for (int r = 0; r < 4; ++r)
                    c3[i][r] = __shfl(nc[r], (lane & 48) + 15);
            }
        }
        __syncthreads();

        // ---- LayerNorm rows -> out ----
        for (int r = w; r < mt; r += 4) {
            float2 v = *(const float2*)&F[r * SF + lane * 2];
            float s1 = v.x + v.y;
            float s2v = v.x * v.x + v.y * v.y;
#pragma unroll
            for (int off = 32; off > 0; off >>= 1) {
                s1 += __shfl_down(s1, off);
                s2v += __shfl_down(s2v, off);
            }
            s1 = __shfl(s1, 0);
            s2v = __shfl(s2v, 0);
            float mu = s1 * (1.0f / D_OUT);
            float var = s2v * (1.0f / D_OUT) - mu * mu;
            float rstd = rsqrtf(var + 1e-5f);
            float2 o;
            o.x = (v.x - mu) * rstd * gmv.x + btv.x;
            o.y = (v.y - mu) * rstd * gmv.y + btv.y;
            *(float2*)&out[(size_t)sp[r] * D_OUT + lane * 2] = o;
        }
    }
}

// ---------------------------------------------------------------------------

extern "C" void kernel_launch(void* const* d_in, const int* in_sizes, int n_in,
                              void* d_out, int out_size, void* d_ws, size_t ws_size,
                              hipStream_t stream) {
    const float* x     = (const float*)d_in[0];
    const int*   idx   = (const int*)d_in[1];
    const float* W1    = (const float*)d_in[2];
    const float* b1    = (const float*)d_in[3];
    const float* W2    = (const float*)d_in[4];
    const float* b2    = (const float*)d_in[5];
    const float* W3    = (const float*)d_in[6];
    const float* b3    = (const float*)d_in[7];
    const float* gamma = (const float*)d_in[8];
    const float* beta  = (const float*)d_in[9];
    float* out = (float*)d_out;

    char* ws = (char*)d_ws;
    size_t off = 0;
    auto alloc = [&](size_t bytes) -> void* {
        void* p = (void*)(ws + off);
        off += (bytes + 255) & ~(size_t)255;
        return p;
    };
    float* dis   = (float*)alloc(NN * sizeof(float));
    int*   perm  = (int*)alloc(NN * sizeof(int));
    int*   lrank = (int*)alloc(NN * sizeof(int));
    int*   gs    = (int*)alloc((NG + 1) * sizeof(int));
    int*   bhist = (int*)alloc(NG * NB_PAD * sizeof(int));
    int*   boff  = (int*)alloc(NG * NB_PAD * sizeof(int));
    __hip_bfloat16* Wt1 = (__hip_bfloat16*)alloc((size_t)D_IN * H1 * 2);
    __hip_bfloat16* Wt2 = (__hip_bfloat16*)alloc((size_t)H1 * H2 * 2);
    __hip_bfloat16* Wt3 = (__hip_bfloat16*)alloc((size_t)H2 * D_OUT * 2);

    rank1_kernel<<<NB_RANK, 256, 0, stream>>>(idx, lrank, bhist);
    rank2_kernel<<<1, 512, 0, stream>>>(bhist, boff, gs);
    rank3_kernel<<<NB_RANK, 256, 0, stream>>>(idx, lrank, boff, gs, dis, perm);
    wt_all<<<(WT_ELEMS + 255) / 256, 256, 0, stream>>>(
        W1, W2, W3, Wt1, Wt2, Wt3);

    fused_gcn<<<NG, 256, 0, stream>>>(
        x, Wt1, Wt2, Wt3, b1, b2, b3, gamma, beta, dis, perm, gs, out);
}

// Round 8
// 156.527 us; speedup vs baseline: 1.0287x; 1.0287x over previous
//
#include <hip/hip_runtime.h>
#include <hip/hip_bf16.h>

// Problem constants (GCN_66649302499531)
#define NN 20000
#define NG 400
#define D_IN 128
#define H1 256
#define H2 256
#define D_OUT 128
#define NB_RANK ((NN + 255) / 256)   // 79
#define NB_PAD 80
#define WT_ELEMS (D_IN * H1 + H1 * H2 + H2 * D_OUT)   // 131072

typedef __attribute__((ext_vector_type(8))) short short8;
typedef __attribute__((ext_vector_type(4))) short short4v;
typedef __attribute__((ext_vector_type(4))) float floatx4;

__device__ __forceinline__ short f2b(float f) {
    __hip_bfloat16 h = __float2bfloat16(f);
    return *(short*)&h;
}

// ---------------------------------------------------------------------------
// Rank / permutation kernels (R4/R7-proven, separate launches).
// ---------------------------------------------------------------------------

__global__ __launch_bounds__(256) void rank1_kernel(
    const int* __restrict__ idx, int* __restrict__ lrank,
    int* __restrict__ blockhist)
{
    __shared__ int sg[256];
    __shared__ int hist[NG];
    int t = threadIdx.x;
    int b = blockIdx.x;
    int j = b * 256 + t;
    for (int g = t; g < NG; g += 256) hist[g] = 0;
    int g = (j < NN) ? idx[j] : -1;
    sg[t] = g;
    __syncthreads();
    if (g >= 0) atomicAdd(&hist[g], 1);
    int r = 0;
    for (int s = 0; s < t; ++s) {
        if (sg[s] == g) r++;
    }
    __syncthreads();
    if (j < NN) lrank[j] = r;
    for (int gg = t; gg < NG; gg += 256) blockhist[gg * NB_PAD + b] = hist[gg];
}

__global__ __launch_bounds__(512) void rank2_kernel(
    const int* __restrict__ blockhist, int* __restrict__ blockoff,
    int* __restrict__ gs)
{
    __shared__ int tot[512];
    int g = threadIdx.x;
    int run = 0;
    if (g < NG) {
        int4 buf[NB_PAD / 4];
        const int4* src = (const int4*)(blockhist + g * NB_PAD);
#pragma unroll
        for (int i = 0; i < NB_PAD / 4; ++i) buf[i] = src[i];
        const int* bi = (const int*)buf;
#pragma unroll
        for (int b = 0; b < NB_RANK; ++b) {
            blockoff[g * NB_PAD + b] = run;
            run += bi[b];
        }
    }
    tot[threadIdx.x] = (g < NG) ? run : 0;
    __syncthreads();
#pragma unroll
    for (int off = 1; off < 512; off <<= 1) {
        int v = (threadIdx.x >= off) ? tot[threadIdx.x - off] : 0;
        __syncthreads();
        tot[threadIdx.x] += v;
        __syncthreads();
    }
    if (threadIdx.x == 0) gs[0] = 0;
    if (threadIdx.x < NG) gs[threadIdx.x + 1] = tot[threadIdx.x];
}

__global__ __launch_bounds__(256) void rank3_kernel(
    const int* __restrict__ idx, const int* __restrict__ lrank,
    const int* __restrict__ blockoff, const int* __restrict__ gs,
    float* __restrict__ dis, int* __restrict__ perm)
{
    int j = blockIdx.x * 256 + threadIdx.x;
    if (j >= NN) return;
    int g = idx[j];
    int r = blockoff[g * NB_PAD + blockIdx.x] + lrank[j];
    dis[j] = rsqrtf((float)(r + 1));
    perm[gs[g] + r] = j;
}

// ---------------------------------------------------------------------------
// All three weight transposes (fp32 [K][N] -> bf16 [N][K]) in one launch.
// ---------------------------------------------------------------------------

__global__ __launch_bounds__(256) void wt_all(
    const float* __restrict__ W1, const float* __restrict__ W2,
    const float* __restrict__ W3, __hip_bfloat16* __restrict__ Wt1,
    __hip_bfloat16* __restrict__ Wt2, __hip_bfloat16* __restrict__ Wt3)
{
    int o = blockIdx.x * 256 + threadIdx.x;
    if (o < D_IN * H1) {                       // W1: K=128, N=256
        int n = o / D_IN, k = o - n * D_IN;
        Wt1[o] = __float2bfloat16(W1[(size_t)k * H1 + n]);
    } else if (o < D_IN * H1 + H1 * H2) {      // W2: K=256, N=256
        int p = o - D_IN * H1;
        int n = p / H1, k = p - n * H1;
        Wt2[p] = __float2bfloat16(W2[(size_t)k * H2 + n]);
    } else if (o < WT_ELEMS) {                 // W3: K=256, N=128
        int p = o - D_IN * H1 - H1 * H2;
        int n = p / H2, k = p - n * H2;
        Wt3[p] = __float2bfloat16(W3[(size_t)k * D_OUT + n]);
    }
}

// ---------------------------------------------------------------------------
// Fused per-group pipeline (R7 structure). Key change vs R7: each wave's
// weight-fragment slices (Wt1/Wt2/Wt3) are preloaded into REGISTERS once per
// block, so the GEMM K-loops have zero global loads (they were the latency
// bottleneck: 32-64 L2 round trips per stage, serialized by waitcnt). The
// gathered x-load issues all 32 loads in one batch. Triangular scan
// fragments are regenerated per scan stage (cheap VALU) instead of living
// in 32 persistent VGPRs.
// ---------------------------------------------------------------------------

#define ST1 72
#define SA1 136
#define ST2 72
#define SA2 264
#define SH2 264
#define ST3 72
#define SF 132

__global__ __launch_bounds__(256, 1) void fused_gcn(
    const float* __restrict__ x,
    const __hip_bfloat16* __restrict__ Wt1_,
    const __hip_bfloat16* __restrict__ Wt2_,
    const __hip_bfloat16* __restrict__ Wt3_,
    const float* __restrict__ b1, const float* __restrict__ b2,
    const float* __restrict__ b3,
    const float* __restrict__ gamma, const float* __restrict__ beta,
    const float* __restrict__ dis, const int* __restrict__ perm,
    const int* __restrict__ gs,
    float* __restrict__ out)
{
    __shared__ __align__(16) char RA[36864];   // T1 | T2 | HB | F
    __shared__ __align__(16) char RB[33792];   // A1 | A2 | T3
    __shared__ __align__(16) float b2s[256];
    __shared__ __align__(16) float b3s[128];
    __shared__ __align__(16) float sd[64];
    __shared__ int sp[64];

    short* T1 = (short*)RA;
    short* T2 = (short*)RA;
    short* HB = (short*)RA;
    float* F  = (float*)RA;
    short* A1 = (short*)RB;
    short* A2 = (short*)RB;
    short* T3 = (short*)RB;

    const short* Wt1 = (const short*)Wt1_;
    const short* Wt2 = (const short*)Wt2_;
    const short* Wt3 = (const short*)Wt3_;

    int tid = threadIdx.x;
    int w = tid >> 6;
    int lane = tid & 63;
    int quad = lane >> 4;
    int l15 = lane & 15;

    int g = blockIdx.x;
    int s = gs[g], cnt = gs[g + 1] - s;
    if (cnt <= 0) return;

    b2s[tid] = b2[tid];
    if (tid < 128) b3s[tid] = b3[tid];

    float bj1[4];
#pragma unroll
    for (int nt = 0; nt < 4; ++nt) bj1[nt] = b1[(w * 4 + nt) * 16 + l15];
    float2 gmv = *(const float2*)&gamma[lane * 2];
    float2 btv = *(const float2*)&beta[lane * 2];

    // ---- preload per-wave weight fragments into registers (once) ----
    short8 wf1[4][4];   // GEMM1 B-frags: [kk][nt]
#pragma unroll
    for (int kk = 0; kk < 4; ++kk)
#pragma unroll
        for (int nt = 0; nt < 4; ++nt)
            wf1[kk][nt] = *(const short8*)&Wt1[((size_t)(w * 4 + nt) * 16 + l15) * D_IN + kk * 32 + quad * 8];
    short8 wf2[8][4];   // GEMM2 A-frags: [kk][i]
#pragma unroll
    for (int kk = 0; kk < 8; ++kk)
#pragma unroll
        for (int i = 0; i < 4; ++i)
            wf2[kk][i] = *(const short8*)&Wt2[((size_t)(w * 4 + i) * 16 + l15) * H1 + kk * 32 + quad * 8];
    short8 wf3[8][2];   // GEMM3 B-frags: [kk][jn]
#pragma unroll
    for (int kk = 0; kk < 8; ++kk)
#pragma unroll
        for (int jn = 0; jn < 2; ++jn)
            wf3[kk][jn] = *(const short8*)&Wt3[((size_t)(2 * w + jn) * 16 + l15) * H2 + kk * 32 + quad * 8];

    // lower-triangular-ones fragment generator (B-operand of scan MFMAs)
    auto ltfrag = [&](int nt, int k2) -> short8 {
        int thr = nt * 16 + l15 - k2 * 32 - quad * 8;
        short8 f;
#pragma unroll
        for (int e = 0; e < 8; ++e)
            f[e] = (e <= thr) ? (short)0x3F80 : (short)0;
        return f;
    };

    float c1[2][4], c2[4][4], c3[2][4];
#pragma unroll
    for (int i = 0; i < 4; ++i)
#pragma unroll
        for (int r = 0; r < 4; ++r) {
            if (i < 2) { c1[i][r] = 0.f; c3[i][r] = 0.f; }
            c2[i][r] = 0.f;
        }

    for (int base = 0; base < cnt; base += 64) {
        int mt = min(64, cnt - base);
        __syncthreads();   // prev chunk LN done with F/sp
        if (tid < 64) {
            int p = (tid < mt) ? perm[s + base + tid] : perm[s];
            sp[tid] = p;
            sd[tid] = (tid < mt) ? dis[p] : 0.0f;
        }
        __syncthreads();

        float djn[4];
#pragma unroll
        for (int nt = 0; nt < 4; ++nt) djn[nt] = sd[nt * 16 + l15];

        // ---- stage x -> T1: xt[c][r] = bf16(x[sp[r]][c] * sd[r]) ----
        // all 32 gathered loads issued as one batch (one latency round)
        {
            int c = tid & 127;
            int rb0 = (tid >> 7) * 8;
            int rows[32];
            float dd[32];
#pragma unroll
            for (int m = 0; m < 32; ++m) {
                int r = rb0 + (m >> 3) * 16 + (m & 7);
                rows[m] = sp[r];
                dd[m] = sd[r];
            }
            float v[32];
#pragma unroll
            for (int m = 0; m < 32; ++m)
                v[m] = x[(size_t)rows[m] * D_IN + c];
#pragma unroll
            for (int p = 0; p < 4; ++p) {
                short8 o;
#pragma unroll
                for (int e = 0; e < 8; ++e)
                    o[e] = f2b(v[p * 8 + e] * dd[p * 8 + e]);
                *(short8*)&T1[c * ST1 + rb0 + p * 16] = o;
            }
        }
        __syncthreads();

        // ---- scan1 (MFMA): A1[j][c] = dj*(c1 + cumsum) ----
        {
            floatx4 acc[2][4];
#pragma unroll
            for (int i = 0; i < 2; ++i)
#pragma unroll
                for (int nt = 0; nt < 4; ++nt) acc[i][nt] = (floatx4)0.0f;
#pragma unroll
            for (int k2 = 0; k2 < 2; ++k2) {
                short8 af[2];
#pragma unroll
                for (int i = 0; i < 2; ++i)
                    af[i] = *(const short8*)&T1[((2 * w + i) * 16 + l15) * ST1 + k2 * 32 + quad * 8];
#pragma unroll
                for (int nt = 0; nt < 4; ++nt) {
                    short8 lt = ltfrag(nt, k2);
#pragma unroll
                    for (int i = 0; i < 2; ++i)
                        acc[i][nt] = __builtin_amdgcn_mfma_f32_16x16x32_bf16(
                            af[i], lt, acc[i][nt], 0, 0, 0);
                }
            }
#pragma unroll
            for (int i = 0; i < 2; ++i) {
                float nc[4] = {0.f, 0.f, 0.f, 0.f};
#pragma unroll
                for (int nt = 0; nt < 4; ++nt) {
                    float tmp[4];
#pragma unroll
                    for (int r = 0; r < 4; ++r) tmp[r] = acc[i][nt][r] + c1[i][r];
                    if (nt == 3) {
#pragma unroll
                        for (int r = 0; r < 4; ++r) nc[r] = tmp[r];
                    }
                    short4v o4;
#pragma unroll
                    for (int r = 0; r < 4; ++r) o4[r] = f2b(tmp[r] * djn[nt]);
                    *(short4v*)&A1[(nt * 16 + l15) * SA1 + (2 * w + i) * 16 + quad * 4] = o4;
                }
#pragma unroll
                for (int r = 0; r < 4; ++r)
                    c1[i][r] = __shfl(nc[r], (lane & 48) + 15);
            }
        }
        __syncthreads();

        // ---- GEMM1: h1t[c][j] = relu(A1 @ Wt1^T + b1) * sd[j] ----
        {
            floatx4 acc[4][4];
#pragma unroll
            for (int i = 0; i < 4; ++i)
#pragma unroll
                for (int j = 0; j < 4; ++j) acc[i][j] = (floatx4)0.0f;
#pragma unroll
            for (int kk = 0; kk < 4; ++kk) {   // K = 128
                short8 af[4];
#pragma unroll
                for (int i = 0; i < 4; ++i)
                    af[i] = *(const short8*)&A1[(i * 16 + l15) * SA1 + kk * 32 + quad * 8];
#pragma unroll
                for (int i = 0; i < 4; ++i)
#pragma unroll
                    for (int nt = 0; nt < 4; ++nt)
                        acc[i][nt] = __builtin_amdgcn_mfma_f32_16x16x32_bf16(
                            af[i], wf1[kk][nt], acc[i][nt], 0, 0, 0);
            }
#pragma unroll
            for (int i = 0; i < 4; ++i) {
                float4 sdv = *(const float4*)&sd[i * 16 + quad * 4];   // sd[j]
#pragma unroll
                for (int nt = 0; nt < 4; ++nt) {
                    short4v o4;
                    o4[0] = f2b(fmaxf(acc[i][nt][0] + bj1[nt], 0.0f) * sdv.x);
                    o4[1] = f2b(fmaxf(acc[i][nt][1] + bj1[nt], 0.0f) * sdv.y);
                    o4[2] = f2b(fmaxf(acc[i][nt][2] + bj1[nt], 0.0f) * sdv.z);
                    o4[3] = f2b(fmaxf(acc[i][nt][3] + bj1[nt], 0.0f) * sdv.w);
                    *(short4v*)&T2[((w * 4 + nt) * 16 + l15) * ST2 + i * 16 + quad * 4] = o4;
                }
            }
        }
        __syncthreads();

        // ---- scan2 (MFMA): A2[j][c] = dj*(c2 + cumsum(h1t)) ----
        {
            floatx4 acc[4][4];
#pragma unroll
            for (int i = 0; i < 4; ++i)
#pragma unroll
                for (int nt = 0; nt < 4; ++nt) acc[i][nt] = (floatx4)0.0f;
#pragma unroll
            for (int k2 = 0; k2 < 2; ++k2) {
                short8 af[4];
#pragma unroll
                for (int i = 0; i < 4; ++i)
                    af[i] = *(const short8*)&T2[((4 * w + i) * 16 + l15) * ST2 + k2 * 32 + quad * 8];
#pragma unroll
                for (int nt = 0; nt < 4; ++nt) {
                    short8 lt = ltfrag(nt, k2);
#pragma unroll
                    for (int i = 0; i < 4; ++i)
                        acc[i][nt] = __builtin_amdgcn_mfma_f32_16x16x32_bf16(
                            af[i], lt, acc[i][nt], 0, 0, 0);
                }
            }
#pragma unroll
            for (int i = 0; i < 4; ++i) {
                float nc[4] = {0.f, 0.f, 0.f, 0.f};
#pragma unroll
                for (int nt = 0; nt < 4; ++nt) {
                    float tmp[4];
#pragma unroll
                    for (int r = 0; r < 4; ++r) tmp[r] = acc[i][nt][r] + c2[i][r];
                    if (nt == 3) {
#pragma unroll
                        for (int r = 0; r < 4; ++r) nc[r] = tmp[r];
                    }
                    short4v o4;
#pragma unroll
                    for (int r = 0; r < 4; ++r) o4[r] = f2b(tmp[r] * djn[nt]);
                    *(short4v*)&A2[(nt * 16 + l15) * SA2 + (4 * w + i) * 16 + quad * 4] = o4;
                }
#pragma unroll
                for (int r = 0; r < 4; ++r)
                    c2[i][r] = __shfl(nc[r], (lane & 48) + 15);
            }
        }
        __syncthreads();

        // ---- GEMM2: h2[j][c2] = relu(A2 @ Wt2^T + b2)  (A=Wt2, B=A2) ----
        {
            floatx4 acc[4][4];
#pragma unroll
            for (int i = 0; i < 4; ++i)
#pragma unroll
                for (int nt = 0; nt < 4; ++nt) acc[i][nt] = (floatx4)0.0f;
#pragma unroll
            for (int kk = 0; kk < 8; ++kk) {   // K = 256
                short8 bf[4];
#pragma unroll
                for (int nt = 0; nt < 4; ++nt)
                    bf[nt] = *(const short8*)&A2[(nt * 16 + l15) * SA2 + kk * 32 + quad * 8];
#pragma unroll
                for (int i = 0; i < 4; ++i)
#pragma unroll
                    for (int nt = 0; nt < 4; ++nt)
                        acc[i][nt] = __builtin_amdgcn_mfma_f32_16x16x32_bf16(
                            wf2[kk][i], bf[nt], acc[i][nt], 0, 0, 0);
            }
#pragma unroll
            for (int i = 0; i < 4; ++i) {
                float4 bb = *(const float4*)&b2s[(w * 4 + i) * 16 + quad * 4];
#pragma unroll
                for (int nt = 0; nt < 4; ++nt) {
                    short4v o4;
                    o4[0] = f2b(fmaxf(acc[i][nt][0] + bb.x, 0.0f));
                    o4[1] = f2b(fmaxf(acc[i][nt][1] + bb.y, 0.0f));
                    o4[2] = f2b(fmaxf(acc[i][nt][2] + bb.z, 0.0f));
                    o4[3] = f2b(fmaxf(acc[i][nt][3] + bb.w, 0.0f));
                    *(short4v*)&HB[(nt * 16 + l15) * SH2 + (w * 4 + i) * 16 + quad * 4] = o4;
                }
            }
        }
        __syncthreads();

        // ---- GEMM3: Pt[d][j] = (h2 @ Wt3^T)[j][d] * sd[j]  (A=HB, B=Wt3) ----
        {
            floatx4 acc[4][2];
#pragma unroll
            for (int i = 0; i < 4; ++i)
#pragma unroll
                for (int jn = 0; jn < 2; ++jn) acc[i][jn] = (floatx4)0.0f;
#pragma unroll
            for (int kk = 0; kk < 8; ++kk) {   // K = 256
                short8 af[4];
#pragma unroll
                for (int i = 0; i < 4; ++i)
                    af[i] = *(const short8*)&HB[(i * 16 + l15) * SH2 + kk * 32 + quad * 8];
#pragma unroll
                for (int i = 0; i < 4; ++i)
#pragma unroll
                    for (int jn = 0; jn < 2; ++jn)
                        acc[i][jn] = __builtin_amdgcn_mfma_f32_16x16x32_bf16(
                            af[i], wf3[kk][jn], acc[i][jn], 0, 0, 0);
            }
#pragma unroll
            for (int i = 0; i < 4; ++i) {
                float4 sdv = *(const float4*)&sd[i * 16 + quad * 4];
#pragma unroll
                for (int jn = 0; jn < 2; ++jn) {
                    short4v o4;
                    o4[0] = f2b(acc[i][jn][0] * sdv.x);
                    o4[1] = f2b(acc[i][jn][1] * sdv.y);
                    o4[2] = f2b(acc[i][jn][2] * sdv.z);
                    o4[3] = f2b(acc[i][jn][3] * sdv.w);
                    *(short4v*)&T3[((2 * w + jn) * 16 + l15) * ST3 + i * 16 + quad * 4] = o4;
                }
            }
        }
        __syncthreads();

        // ---- scan3 (MFMA): F[j][d] = relu(dj*(c3 + cumsum(Pt)) + b3) fp32 ----
        {
            floatx4 acc[2][4];
#pragma unroll
            for (int i = 0; i < 2; ++i)
#pragma unroll
                for (int nt = 0; nt < 4; ++nt) acc[i][nt] = (floatx4)0.0f;
#pragma unroll
            for (int k2 = 0; k2 < 2; ++k2) {
                short8 af[2];
#pragma unroll
                for (int i = 0; i < 2; ++i)
                    af[i] = *(const short8*)&T3[((2 * w + i) * 16 + l15) * ST3 + k2 * 32 + quad * 8];
#pragma unroll
                for (int nt = 0; nt < 4; ++nt) {
                    short8 lt = ltfrag(nt, k2);
#pragma unroll
                    for (int i = 0; i < 2; ++i)
                        acc[i][nt] = __builtin_amdgcn_mfma_f32_16x16x32_bf16(
                            af[i], lt, acc[i][nt], 0, 0, 0);
                }
            }
#pragma unroll
            for (int i = 0; i < 2; ++i) {
                float4 bb = *(const float4*)&b3s[(2 * w + i) * 16 + quad * 4];
                float nc[4] = {0.f, 0.f, 0.f, 0.f};
#pragma unroll
                for (int nt = 0; nt < 4; ++nt) {
                    float tmp[4];
#pragma unroll
                    for (int r = 0; r < 4; ++r) tmp[r] = acc[i][nt][r] + c3[i][r];
                    if (nt == 3) {
#pragma unroll
                        for (int r = 0; r < 4; ++r) nc[r] = tmp[r];
                    }
                    float4 o;
                    o.x = fmaxf(tmp[0] * djn[nt] + bb.x, 0.0f);
                    o.y = fmaxf(tmp[1] * djn[nt] + bb.y, 0.0f);
                    o.z = fmaxf(tmp[2] * djn[nt] + bb.z, 0.0f);
                    o.w = fmaxf(tmp[3] * djn[nt] + bb.w, 0.0f);
                    *(float4*)&F[(nt * 16 + l15) * SF + (2 * w + i) * 16 + quad * 4] = o;
                }
#pragma unroll
                for (int r = 0; r < 4; ++r)
                    c3[i][r] = __shfl(nc[r], (lane & 48) + 15);
            }
        }
        __syncthreads();

        // ---- LayerNorm rows -> out ----
        for (int r = w; r < mt; r += 4) {
            float2 v = *(const float2*)&F[r * SF + lane * 2];
            float s1 = v.x + v.y;
            float s2v = v.x * v.x + v.y * v.y;
#pragma unroll
            for (int off = 32; off > 0; off >>= 1) {
                s1 += __shfl_down(s1, off);
                s2v += __shfl_down(s2v, off);
            }
            s1 = __shfl(s1, 0);
            s2v = __shfl(s2v, 0);
            float mu = s1 * (1.0f / D_OUT);
            float var = s2v * (1.0f / D_OUT) - mu * mu;
            float rstd = rsqrtf(var + 1e-5f);
            float2 o;
            o.x = (v.x - mu) * rstd * gmv.x + btv.x;
            o.y = (v.y - mu) * rstd * gmv.y + btv.y;
            *(float2*)&out[(size_t)sp[r] * D_OUT + lane * 2] = o;
        }
    }
}

// ---------------------------------------------------------------------------

extern "C" void kernel_launch(void* const* d_in, const int* in_sizes, int n_in,
                              void* d_out, int out_size, void* d_ws, size_t ws_size,
                              hipStream_t stream) {
    const float* x     = (const float*)d_in[0];
    const int*   idx   = (const int*)d_in[1];
    const float* W1    = (const float*)d_in[2];
    const float* b1    = (const float*)d_in[3];
    const float* W2    = (const float*)d_in[4];
    const float* b2    = (const float*)d_in[5];
    const float* W3    = (const float*)d_in[6];
    const float* b3    = (const float*)d_in[7];
    const float* gamma = (const float*)d_in[8];
    const float* beta  = (const float*)d_in[9];
    float* out = (float*)d_out;

    char* ws = (char*)d_ws;
    size_t off = 0;
    auto alloc = [&](size_t bytes) -> void* {
        void* p = (void*)(ws + off);
        off += (bytes + 255) & ~(size_t)255;
        return p;
    };
    float* dis   = (float*)alloc(NN * sizeof(float));
    int*   perm  = (int*)alloc(NN * sizeof(int));
    int*   lrank = (int*)alloc(NN * sizeof(int));
    int*   gs    = (int*)alloc((NG + 1) * sizeof(int));
    int*   bhist = (int*)alloc(NG * NB_PAD * sizeof(int));
    int*   boff  = (int*)alloc(NG * NB_PAD * sizeof(int));
    __hip_bfloat16* Wt1 = (__hip_bfloat16*)alloc((size_t)D_IN * H1 * 2);
    __hip_bfloat16* Wt2 = (__hip_bfloat16*)alloc((size_t)H1 * H2 * 2);
    __hip_bfloat16* Wt3 = (__hip_bfloat16*)alloc((size_t)H2 * D_OUT * 2);

    rank1_kernel<<<NB_RANK, 256, 0, stream>>>(idx, lrank, bhist);
    rank2_kernel<<<1, 512, 0, stream>>>(bhist, boff, gs);
    rank3_kernel<<<NB_RANK, 256, 0, stream>>>(idx, lrank, boff, gs, dis, perm);
    wt_all<<<(WT_ELEMS + 255) / 256, 256, 0, stream>>>(
        W1, W2, W3, Wt1, Wt2, Wt3);

    fused_gcn<<<NG, 256, 0, stream>>>(
        x, Wt1, Wt2, Wt3, b1, b2, b3, gamma, beta, dis, perm, gs, out);
}

// Round 9
// 156.311 us; speedup vs baseline: 1.0301x; 1.0014x over previous
//
#include <hip/hip_runtime.h>
#include <hip/hip_bf16.h>

// Problem constants (GCN_66649302499531)
#define NN 20000
#define NG 400
#define D_IN 128
#define H1 256
#define H2 256
#define D_OUT 128
#define NB_RANK ((NN + 255) / 256)   // 79
#define NB_PAD 80
#define WT_ELEMS (D_IN * H1 + H1 * H2 + H2 * D_OUT)   // 131072

typedef __attribute__((ext_vector_type(8))) short short8;
typedef __attribute__((ext_vector_type(4))) short short4v;
typedef __attribute__((ext_vector_type(4))) float floatx4;

__device__ __forceinline__ short f2b(float f) {
    __hip_bfloat16 h = __float2bfloat16(f);
    return *(short*)&h;
}

// async global->LDS DMA, 16B per lane: lane i reads its own global addr,
// writes wave-uniform lds base + i*16 (m104 semantics).
__device__ __forceinline__ void gl_lds16(const void* g, void* l) {
    __builtin_amdgcn_global_load_lds(
        (__attribute__((address_space(1))) void*)g,
        (__attribute__((address_space(3))) void*)l, 16, 0, 0);
}

// ---------------------------------------------------------------------------
// Rank / permutation kernels (R4/R7-proven, separate launches).
// ---------------------------------------------------------------------------

__global__ __launch_bounds__(256) void rank1_kernel(
    const int* __restrict__ idx, int* __restrict__ lrank,
    int* __restrict__ blockhist)
{
    __shared__ int sg[256];
    __shared__ int hist[NG];
    int t = threadIdx.x;
    int b = blockIdx.x;
    int j = b * 256 + t;
    for (int g = t; g < NG; g += 256) hist[g] = 0;
    int g = (j < NN) ? idx[j] : -1;
    sg[t] = g;
    __syncthreads();
    if (g >= 0) atomicAdd(&hist[g], 1);
    int r = 0;
    for (int s = 0; s < t; ++s) {
        if (sg[s] == g) r++;
    }
    __syncthreads();
    if (j < NN) lrank[j] = r;
    for (int gg = t; gg < NG; gg += 256) blockhist[gg * NB_PAD + b] = hist[gg];
}

__global__ __launch_bounds__(512) void rank2_kernel(
    const int* __restrict__ blockhist, int* __restrict__ blockoff,
    int* __restrict__ gs)
{
    __shared__ int tot[512];
    int g = threadIdx.x;
    int run = 0;
    if (g < NG) {
        int4 buf[NB_PAD / 4];
        const int4* src = (const int4*)(blockhist + g * NB_PAD);
#pragma unroll
        for (int i = 0; i < NB_PAD / 4; ++i) buf[i] = src[i];
        const int* bi = (const int*)buf;
#pragma unroll
        for (int b = 0; b < NB_RANK; ++b) {
            blockoff[g * NB_PAD + b] = run;
            run += bi[b];
        }
    }
    tot[threadIdx.x] = (g < NG) ? run : 0;
    __syncthreads();
#pragma unroll
    for (int off = 1; off < 512; off <<= 1) {
        int v = (threadIdx.x >= off) ? tot[threadIdx.x - off] : 0;
        __syncthreads();
        tot[threadIdx.x] += v;
        __syncthreads();
    }
    if (threadIdx.x == 0) gs[0] = 0;
    if (threadIdx.x < NG) gs[threadIdx.x + 1] = tot[threadIdx.x];
}

__global__ __launch_bounds__(256) void rank3_kernel(
    const int* __restrict__ idx, const int* __restrict__ lrank,
    const int* __restrict__ blockoff, const int* __restrict__ gs,
    float* __restrict__ dis, int* __restrict__ perm)
{
    int j = blockIdx.x * 256 + threadIdx.x;
    if (j >= NN) return;
    int g = idx[j];
    int r = blockoff[g * NB_PAD + blockIdx.x] + lrank[j];
    dis[j] = rsqrtf((float)(r + 1));
    perm[gs[g] + r] = j;
}

// ---------------------------------------------------------------------------
// All three weight transposes (fp32 [K][N] -> bf16 [N][K]) in one launch.
// ---------------------------------------------------------------------------

__global__ __launch_bounds__(256) void wt_all(
    const float* __restrict__ W1, const float* __restrict__ W2,
    const float* __restrict__ W3, __hip_bfloat16* __restrict__ Wt1,
    __hip_bfloat16* __restrict__ Wt2, __hip_bfloat16* __restrict__ Wt3)
{
    int o = blockIdx.x * 256 + threadIdx.x;
    if (o < D_IN * H1) {                       // W1: K=128, N=256
        int n = o / D_IN, k = o - n * D_IN;
        Wt1[o] = __float2bfloat16(W1[(size_t)k * H1 + n]);
    } else if (o < D_IN * H1 + H1 * H2) {      // W2: K=256, N=256
        int p = o - D_IN * H1;
        int n = p / H1, k = p - n * H1;
        Wt2[p] = __float2bfloat16(W2[(size_t)k * H2 + n]);
    } else if (o < WT_ELEMS) {                 // W3: K=256, N=128
        int p = o - D_IN * H1 - H1 * H2;
        int n = p / H2, k = p - n * H2;
        Wt3[p] = __float2bfloat16(W3[(size_t)k * D_OUT + n]);
    }
}

// ---------------------------------------------------------------------------
// Fused per-group pipeline. R9 changes vs R8 (anti-spill):
//  - stage-x via global_load_lds DMA (zero VGPR cost, one latency round)
//    into XR (fp32 row-major), then a small-register LDS repack -> T1.
//  - weights loaded from global (L2-hot) inside K-loops; NO register preload.
//  - Lt triangular frags regenerated per scan stage.
//  Arch-VGPR ceiling is 256; R7/R8 spilled ~14-19 MB/dispatch to scratch
//  (WRITE_SIZE evidence) — this version must fit.
// ---------------------------------------------------------------------------

#define ST1 72
#define SA1 136
#define ST2 72
#define SA2 264
#define SH2 264
#define ST3 72
#define SF 132

__global__ __launch_bounds__(256) void fused_gcn(
    const float* __restrict__ x,
    const __hip_bfloat16* __restrict__ Wt1_,
    const __hip_bfloat16* __restrict__ Wt2_,
    const __hip_bfloat16* __restrict__ Wt3_,
    const float* __restrict__ b1, const float* __restrict__ b2,
    const float* __restrict__ b3,
    const float* __restrict__ gamma, const float* __restrict__ beta,
    const float* __restrict__ dis, const int* __restrict__ perm,
    const int* __restrict__ gs,
    float* __restrict__ out)
{
    __shared__ __align__(16) char RA[36864];   // XR | T2 | HB | F
    __shared__ __align__(16) char RB[36864];   // T1+A1 | A2 | T3
    __shared__ __align__(16) float b2s[256];
    __shared__ __align__(16) float b3s[128];
    __shared__ __align__(16) float sd[64];
    __shared__ int sp[64];

    float* XR = (float*)RA;                    // 64 x 128 fp32 = 32768 B
    short* T2 = (short*)RA;                    // 128 x 72 bf16 = 18432 B
    short* HB = (short*)RA;                    // 64 x 264 bf16 = 33792 B
    float* F  = (float*)RA;                    // 64 x 132 fp32 = 33792 B
    short* T1 = (short*)RB;                    // 128 x 72 bf16 = 18432 B
    short* A1 = (short*)(RB + 18432);          // 64 x 136 bf16 = 17408 B
    short* A2 = (short*)RB;                    // 64 x 264 bf16 = 33792 B
    short* T3 = (short*)RB;                    // 128 x 72 bf16 (uses 64 rows)

    const short* Wt1 = (const short*)Wt1_;
    const short* Wt2 = (const short*)Wt2_;
    const short* Wt3 = (const short*)Wt3_;

    int tid = threadIdx.x;
    int w = tid >> 6;
    int lane = tid & 63;
    int quad = lane >> 4;
    int l15 = lane & 15;

    int g = blockIdx.x;
    int s = gs[g], cnt = gs[g + 1] - s;
    if (cnt <= 0) return;

    b2s[tid] = b2[tid];
    if (tid < 128) b3s[tid] = b3[tid];

    float bj1[4];
#pragma unroll
    for (int nt = 0; nt < 4; ++nt) bj1[nt] = b1[(w * 4 + nt) * 16 + l15];
    float2 gmv = *(const float2*)&gamma[lane * 2];
    float2 btv = *(const float2*)&beta[lane * 2];

    // lower-triangular-ones frag generator (B-operand of scan MFMAs)
    auto ltfrag = [&](int nt, int k2) -> short8 {
        int thr = nt * 16 + l15 - k2 * 32 - quad * 8;
        short8 f;
#pragma unroll
        for (int e = 0; e < 8; ++e)
            f[e] = (e <= thr) ? (short)0x3F80 : (short)0;
        return f;
    };

    float c1[2][4], c2[4][4], c3[2][4];
#pragma unroll
    for (int i = 0; i < 4; ++i)
#pragma unroll
        for (int r = 0; r < 4; ++r) {
            if (i < 2) { c1[i][r] = 0.f; c3[i][r] = 0.f; }
            c2[i][r] = 0.f;
        }

    for (int base = 0; base < cnt; base += 64) {
        int mt = min(64, cnt - base);
        __syncthreads();   // prev chunk LN done with F/sp
        if (tid < 64) {
            int p = (tid < mt) ? perm[s + base + tid] : perm[s];
            sp[tid] = p;
            sd[tid] = (tid < mt) ? dis[p] : 0.0f;
        }
        __syncthreads();

        float djn[4];
#pragma unroll
        for (int nt = 0; nt < 4; ++nt) djn[nt] = sd[nt * 16 + l15];

        // ---- stage x: DMA 64 rows of x into XR (fp32 row-major) ----
        // wave w covers rows 16w..16w+15; 8 DMA insts x (64 lanes x 16B = 2 rows)
        {
            int r0 = 16 * w;
#pragma unroll
            for (int ii = 0; ii < 8; ++ii) {
                int row = r0 + 2 * ii + (lane >> 5);
                const float* src = x + (size_t)sp[row] * D_IN + (lane & 31) * 4;
                gl_lds16(src, &XR[(r0 + 2 * ii) * D_IN]);
            }
        }
        __syncthreads();   // drains DMA (vmcnt) + lgkm

        // ---- repack: T1[c][r] = bf16(XR[r][c] * sd[r]) ----
        {
            int c = tid & 127;
            int rh = (tid >> 7) * 8;   // 0 or 8
#pragma unroll
            for (int p = 0; p < 4; ++p) {
                int rb = rh + p * 16;
                short8 o;
#pragma unroll
                for (int e = 0; e < 8; ++e)
                    o[e] = f2b(XR[(rb + e) * D_IN + c] * sd[rb + e]);
                *(short8*)&T1[c * ST1 + rb] = o;
            }
        }
        __syncthreads();

        // ---- scan1 (MFMA): A1[j][c] = dj*(c1 + cumsum(T1)) ----
        {
            floatx4 acc[2][4];
#pragma unroll
            for (int i = 0; i < 2; ++i)
#pragma unroll
                for (int nt = 0; nt < 4; ++nt) acc[i][nt] = (floatx4)0.0f;
#pragma unroll
            for (int k2 = 0; k2 < 2; ++k2) {
                short8 af[2];
#pragma unroll
                for (int i = 0; i < 2; ++i)
                    af[i] = *(const short8*)&T1[((2 * w + i) * 16 + l15) * ST1 + k2 * 32 + quad * 8];
#pragma unroll
                for (int nt = 0; nt < 4; ++nt) {
                    short8 lt = ltfrag(nt, k2);
#pragma unroll
                    for (int i = 0; i < 2; ++i)
                        acc[i][nt] = __builtin_amdgcn_mfma_f32_16x16x32_bf16(
                            af[i], lt, acc[i][nt], 0, 0, 0);
                }
            }
#pragma unroll
            for (int i = 0; i < 2; ++i) {
                float nc[4] = {0.f, 0.f, 0.f, 0.f};
#pragma unroll
                for (int nt = 0; nt < 4; ++nt) {
                    float tmp[4];
#pragma unroll
                    for (int r = 0; r < 4; ++r) tmp[r] = acc[i][nt][r] + c1[i][r];
                    if (nt == 3) {
#pragma unroll
                        for (int r = 0; r < 4; ++r) nc[r] = tmp[r];
                    }
                    short4v o4;
#pragma unroll
                    for (int r = 0; r < 4; ++r) o4[r] = f2b(tmp[r] * djn[nt]);
                    *(short4v*)&A1[(nt * 16 + l15) * SA1 + (2 * w + i) * 16 + quad * 4] = o4;
                }
#pragma unroll
                for (int r = 0; r < 4; ++r)
                    c1[i][r] = __shfl(nc[r], (lane & 48) + 15);
            }
        }
        __syncthreads();

        // ---- GEMM1: h1t[c][j] = relu(A1 @ Wt1^T + b1) * sd[j] -> T2 ----
        {
            floatx4 acc[4][4];
#pragma unroll
            for (int i = 0; i < 4; ++i)
#pragma unroll
                for (int j = 0; j < 4; ++j) acc[i][j] = (floatx4)0.0f;
#pragma unroll
            for (int kk = 0; kk < 4; ++kk) {   // K = 128
                short8 af[4], bf[4];
#pragma unroll
                for (int i = 0; i < 4; ++i)
                    af[i] = *(const short8*)&A1[(i * 16 + l15) * SA1 + kk * 32 + quad * 8];
#pragma unroll
                for (int nt = 0; nt < 4; ++nt)
                    bf[nt] = *(const short8*)&Wt1[((size_t)(w * 4 + nt) * 16 + l15) * D_IN + kk * 32 + quad * 8];
#pragma unroll
                for (int i = 0; i < 4; ++i)
#pragma unroll
                    for (int nt = 0; nt < 4; ++nt)
                        acc[i][nt] = __builtin_amdgcn_mfma_f32_16x16x32_bf16(
                            af[i], bf[nt], acc[i][nt], 0, 0, 0);
            }
#pragma unroll
            for (int i = 0; i < 4; ++i) {
                float4 sdv = *(const float4*)&sd[i * 16 + quad * 4];   // sd[j]
#pragma unroll
                for (int nt = 0; nt < 4; ++nt) {
                    short4v o4;
                    o4[0] = f2b(fmaxf(acc[i][nt][0] + bj1[nt], 0.0f) * sdv.x);
                    o4[1] = f2b(fmaxf(acc[i][nt][1] + bj1[nt], 0.0f) * sdv.y);
                    o4[2] = f2b(fmaxf(acc[i][nt][2] + bj1[nt], 0.0f) * sdv.z);
                    o4[3] = f2b(fmaxf(acc[i][nt][3] + bj1[nt], 0.0f) * sdv.w);
                    *(short4v*)&T2[((w * 4 + nt) * 16 + l15) * ST2 + i * 16 + quad * 4] = o4;
                }
            }
        }
        __syncthreads();

        // ---- scan2 (MFMA): A2[j][c] = dj*(c2 + cumsum(T2)) ----
        {
            floatx4 acc[4][4];
#pragma unroll
            for (int i = 0; i < 4; ++i)
#pragma unroll
                for (int nt = 0; nt < 4; ++nt) acc[i][nt] = (floatx4)0.0f;
#pragma unroll
            for (int k2 = 0; k2 < 2; ++k2) {
                short8 af[4];
#pragma unroll
                for (int i = 0; i < 4; ++i)
                    af[i] = *(const short8*)&T2[((4 * w + i) * 16 + l15) * ST2 + k2 * 32 + quad * 8];
#pragma unroll
                for (int nt = 0; nt < 4; ++nt) {
                    short8 lt = ltfrag(nt, k2);
#pragma unroll
                    for (int i = 0; i < 4; ++i)
                        acc[i][nt] = __builtin_amdgcn_mfma_f32_16x16x32_bf16(
                            af[i], lt, acc[i][nt], 0, 0, 0);
                }
            }
#pragma unroll
            for (int i = 0; i < 4; ++i) {
                float nc[4] = {0.f, 0.f, 0.f, 0.f};
#pragma unroll
                for (int nt = 0; nt < 4; ++nt) {
                    float tmp[4];
#pragma unroll
                    for (int r = 0; r < 4; ++r) tmp[r] = acc[i][nt][r] + c2[i][r];
                    if (nt == 3) {
#pragma unroll
                        for (int r = 0; r < 4; ++r) nc[r] = tmp[r];
                    }
                    short4v o4;
#pragma unroll
                    for (int r = 0; r < 4; ++r) o4[r] = f2b(tmp[r] * djn[nt]);
                    *(short4v*)&A2[(nt * 16 + l15) * SA2 + (4 * w + i) * 16 + quad * 4] = o4;
                }
#pragma unroll
                for (int r = 0; r < 4; ++r)
                    c2[i][r] = __shfl(nc[r], (lane & 48) + 15);
            }
        }
        __syncthreads();

        // ---- GEMM2: h2[j][c2] = relu(A2 @ Wt2^T + b2) -> HB  (A=Wt2, B=A2) ----
        {
            floatx4 acc[4][4];
#pragma unroll
            for (int i = 0; i < 4; ++i)
#pragma unroll
                for (int nt = 0; nt < 4; ++nt) acc[i][nt] = (floatx4)0.0f;
#pragma unroll
            for (int kk = 0; kk < 8; ++kk) {   // K = 256
                short8 af[4], bf[4];
#pragma unroll
                for (int i = 0; i < 4; ++i)
                    af[i] = *(const short8*)&Wt2[((size_t)(w * 4 + i) * 16 + l15) * H1 + kk * 32 + quad * 8];
#pragma unroll
                for (int nt = 0; nt < 4; ++nt)
                    bf[nt] = *(const short8*)&A2[(nt * 16 + l15) * SA2 + kk * 32 + quad * 8];
#pragma unroll
                for (int i = 0; i < 4; ++i)
#pragma unroll
                    for (int nt = 0; nt < 4; ++nt)
                        acc[i][nt] = __builtin_amdgcn_mfma_f32_16x16x32_bf16(
                            af[i], bf[nt], acc[i][nt], 0, 0, 0);
            }
#pragma unroll
            for (int i = 0; i < 4; ++i) {
                float4 bb = *(const float4*)&b2s[(w * 4 + i) * 16 + quad * 4];
#pragma unroll
                for (int nt = 0; nt < 4; ++nt) {
                    short4v o4;
                    o4[0] = f2b(fmaxf(acc[i][nt][0] + bb.x, 0.0f));
                    o4[1] = f2b(fmaxf(acc[i][nt][1] + bb.y, 0.0f));
                    o4[2] = f2b(fmaxf(acc[i][nt][2] + bb.z, 0.0f));
                    o4[3] = f2b(fmaxf(acc[i][nt][3] + bb.w, 0.0f));
                    *(short4v*)&HB[(nt * 16 + l15) * SH2 + (w * 4 + i) * 16 + quad * 4] = o4;
                }
            }
        }
        __syncthreads();

        // ---- GEMM3: Pt[d][j] = (h2 @ Wt3^T)[j][d] * sd[j] -> T3 ----
        {
            floatx4 acc[4][2];
#pragma unroll
            for (int i = 0; i < 4; ++i)
#pragma unroll
                for (int jn = 0; jn < 2; ++jn) acc[i][jn] = (floatx4)0.0f;
#pragma unroll
            for (int kk = 0; kk < 8; ++kk) {   // K = 256
                short8 af[4], bf[2];
#pragma unroll
                for (int i = 0; i < 4; ++i)
                    af[i] = *(const short8*)&HB[(i * 16 + l15) * SH2 + kk * 32 + quad * 8];
#pragma unroll
                for (int jn = 0; jn < 2; ++jn)
                    bf[jn] = *(const short8*)&Wt3[((size_t)(2 * w + jn) * 16 + l15) * H2 + kk * 32 + quad * 8];
#pragma unroll
                for (int i = 0; i < 4; ++i)
#pragma unroll
                    for (int jn = 0; jn < 2; ++jn)
                        acc[i][jn] = __builtin_amdgcn_mfma_f32_16x16x32_bf16(
                            af[i], bf[jn], acc[i][jn], 0, 0, 0);
            }
#pragma unroll
            for (int i = 0; i < 4; ++i) {
                float4 sdv = *(const float4*)&sd[i * 16 + quad * 4];
#pragma unroll
                for (int jn = 0; jn < 2; ++jn) {
                    short4v o4;
                    o4[0] = f2b(acc[i][jn][0] * sdv.x);
                    o4[1] = f2b(acc[i][jn][1] * sdv.y);
                    o4[2] = f2b(acc[i][jn][2] * sdv.z);
                    o4[3] = f2b(acc[i][jn][3] * sdv.w);
                    *(short4v*)&T3[((2 * w + jn) * 16 + l15) * ST3 + i * 16 + quad * 4] = o4;
                }
            }
        }
        __syncthreads();

        // ---- scan3 (MFMA): F[j][d] = relu(dj*(c3 + cumsum(T3)) + b3) fp32 ----
        {
            floatx4 acc[2][4];
#pragma unroll
            for (int i = 0; i < 2; ++i)
#pragma unroll
                for (int nt = 0; nt < 4; ++nt) acc[i][nt] = (floatx4)0.0f;
#pragma unroll
            for (int k2 = 0; k2 < 2; ++k2) {
                short8 af[2];
#pragma unroll
                for (int i = 0; i < 2; ++i)
                    af[i] = *(const short8*)&T3[((2 * w + i) * 16 + l15) * ST3 + k2 * 32 + quad * 8];
#pragma unroll
                for (int nt = 0; nt < 4; ++nt) {
                    short8 lt = ltfrag(nt, k2);
#pragma unroll
                    for (int i = 0; i < 2; ++i)
                        acc[i][nt] = __builtin_amdgcn_mfma_f32_16x16x32_bf16(
                            af[i], lt, acc[i][nt], 0, 0, 0);
                }
            }
#pragma unroll
            for (int i = 0; i < 2; ++i) {
                float4 bb = *(const float4*)&b3s[(2 * w + i) * 16 + quad * 4];
                float nc[4] = {0.f, 0.f, 0.f, 0.f};
#pragma unroll
                for (int nt = 0; nt < 4; ++nt) {
                    float tmp[4];
#pragma unroll
                    for (int r = 0; r < 4; ++r) tmp[r] = acc[i][nt][r] + c3[i][r];
                    if (nt == 3) {
#pragma unroll
                        for (int r = 0; r < 4; ++r) nc[r] = tmp[r];
                    }
                    float4 o;
                    o.x = fmaxf(tmp[0] * djn[nt] + bb.x, 0.0f);
                    o.y = fmaxf(tmp[1] * djn[nt] + bb.y, 0.0f);
                    o.z = fmaxf(tmp[2] * djn[nt] + bb.z, 0.0f);
                    o.w = fmaxf(tmp[3] * djn[nt] + bb.w, 0.0f);
                    *(float4*)&F[(nt * 16 + l15) * SF + (2 * w + i) * 16 + quad * 4] = o;
                }
#pragma unroll
                for (int r = 0; r < 4; ++r)
                    c3[i][r] = __shfl(nc[r], (lane & 48) + 15);
            }
        }
        __syncthreads();

        // ---- LayerNorm rows -> out ----
        for (int r = w; r < mt; r += 4) {
            float2 v = *(const float2*)&F[r * SF + lane * 2];
            float s1 = v.x + v.y;
            float s2v = v.x * v.x + v.y * v.y;
#pragma unroll
            for (int off = 32; off > 0; off >>= 1) {
                s1 += __shfl_down(s1, off);
                s2v += __shfl_down(s2v, off);
            }
            s1 = __shfl(s1, 0);
            s2v = __shfl(s2v, 0);
            float mu = s1 * (1.0f / D_OUT);
            float var = s2v * (1.0f / D_OUT) - mu * mu;
            float rstd = rsqrtf(var + 1e-5f);
            float2 o;
            o.x = (v.x - mu) * rstd * gmv.x + btv.x;
            o.y = (v.y - mu) * rstd * gmv.y + btv.y;
            *(float2*)&out[(size_t)sp[r] * D_OUT + lane * 2] = o;
        }
    }
}

// ---------------------------------------------------------------------------

extern "C" void kernel_launch(void* const* d_in, const int* in_sizes, int n_in,
                              void* d_out, int out_size, void* d_ws, size_t ws_size,
                              hipStream_t stream) {
    const float* x     = (const float*)d_in[0];
    const int*   idx   = (const int*)d_in[1];
    const float* W1    = (const float*)d_in[2];
    const float* b1    = (const float*)d_in[3];
    const float* W2    = (const float*)d_in[4];
    const float* b2    = (const float*)d_in[5];
    const float* W3    = (const float*)d_in[6];
    const float* b3    = (const float*)d_in[7];
    const float* gamma = (const float*)d_in[8];
    const float* beta  = (const float*)d_in[9];
    float* out = (float*)d_out;

    char* ws = (char*)d_ws;
    size_t off = 0;
    auto alloc = [&](size_t bytes) -> void* {
        void* p = (void*)(ws + off);
        off += (bytes + 255) & ~(size_t)255;
        return p;
    };
    float* dis   = (float*)alloc(NN * sizeof(float));
    int*   perm  = (int*)alloc(NN * sizeof(int));
    int*   lrank = (int*)alloc(NN * sizeof(int));
    int*   gs    = (int*)alloc((NG + 1) * sizeof(int));
    int*   bhist = (int*)alloc(NG * NB_PAD * sizeof(int));
    int*   boff  = (int*)alloc(NG * NB_PAD * sizeof(int));
    __hip_bfloat16* Wt1 = (__hip_bfloat16*)alloc((size_t)D_IN * H1 * 2);
    __hip_bfloat16* Wt2 = (__hip_bfloat16*)alloc((size_t)H1 * H2 * 2);
    __hip_bfloat16* Wt3 = (__hip_bfloat16*)alloc((size_t)H2 * D_OUT * 2);

    rank1_kernel<<<NB_RANK, 256, 0, stream>>>(idx, lrank, bhist);
    rank2_kernel<<<1, 512, 0, stream>>>(bhist, boff, gs);
    rank3_kernel<<<NB_RANK, 256, 0, stream>>>(idx, lrank, boff, gs, dis, perm);
    wt_all<<<(WT_ELEMS + 255) / 256, 256, 0, stream>>>(
        W1, W2, W3, Wt1, Wt2, Wt3);

    fused_gcn<<<NG, 256, 0, stream>>>(
        x, Wt1, Wt2, Wt3, b1, b2, b3, gamma, beta, dis, perm, gs, out);
}